// Round 4
// baseline (707.608 us; speedup 1.0000x reference)
//
#include <hip/hip_runtime.h>
#include <math.h>
#include <float.h>

#define BB 8
#define FF 1024
#define NJ 17
#define CH 512
#define TOK 81
#define RCP_SQRT_C 0.04419417382415922f   // 1/sqrt(512)
#define LP 133                            // LDS row pad (stride%32=5, conflict-free col reads)

typedef short bf16x8 __attribute__((ext_vector_type(8)));   // 8 bf16 = 4 VGPRs
typedef float f32x16 __attribute__((ext_vector_type(16)));  // 32x32 MFMA acc

static __device__ inline unsigned short f2bf(float f) {
    __bf16 h = (__bf16)f;                       // RNE
    return __builtin_bit_cast(unsigned short, h);
}
static __device__ inline float bf2f(unsigned short u) {
    return (float)__builtin_bit_cast(__bf16, u);
}
// single density expression used for ALL density values (consistency by construction)
static __device__ __forceinline__ float densf(float rm, float nz) {
    return expf(-0.5f * (rm * rm)) + nz * 1e-6f;
}

// frag layout: [b][s(32)][h(2)][f(1024)][j(8)] bf16, uint4 index ((b*32+s)*2+h)*1024 + f

// ---------------- kernel 1: mean over joints + sumsq + hi/lo frag write -------
__global__ __launch_bounds__(256) void pool_kernel(const float* __restrict__ x,
                                                   uint4* __restrict__ fhi,
                                                   uint4* __restrict__ flo,
                                                   float* __restrict__ sq,
                                                   unsigned* __restrict__ ctrl,
                                                   unsigned* __restrict__ rmin) {
    const int t = threadIdx.x;
    const int row0 = blockIdx.x * 4;            // 4 rows per block, one wave per row
    if (t < 4) rmin[row0 + t] = 0x7F7FFFFFu;    // FLT_MAX bits (dist >= 0)
    if (blockIdx.x == 0 && t < 16) ctrl[t] = 0u; // dmx[8] + bcnt[8]
    const int wid = t >> 6, lane = t & 63;
    const int row = row0 + wid;
    const int b = row >> 10, f0 = row0 & 1023;
    const float* px = x + (size_t)row * NJ * CH + lane * 8;
    float a[8] = {};
    #pragma unroll
    for (int n = 0; n < NJ; ++n) {
        const float4 v0 = *(const float4*)(px + (size_t)n * CH);
        const float4 v1 = *(const float4*)(px + (size_t)n * CH + 4);
        a[0] += v0.x; a[1] += v0.y; a[2] += v0.z; a[3] += v0.w;
        a[4] += v1.x; a[5] += v1.y; a[6] += v1.z; a[7] += v1.w;
    }
    float ssq = 0.f;
    unsigned short hi[8], lo[8];
    #pragma unroll
    for (int j = 0; j < 8; ++j) {
        const float m = a[j] / 17.0f;
        ssq += m * m;
        hi[j] = f2bf(m);
        lo[j] = f2bf(m - bf2f(hi[j]));
    }
    #pragma unroll
    for (int off = 32; off > 0; off >>= 1) ssq += __shfl_down(ssq, off);
    if (lane == 0) sq[row] = ssq;

    uint4 uh, ul;
    uh.x = (unsigned)hi[0] | ((unsigned)hi[1] << 16);
    uh.y = (unsigned)hi[2] | ((unsigned)hi[3] << 16);
    uh.z = (unsigned)hi[4] | ((unsigned)hi[5] << 16);
    uh.w = (unsigned)hi[6] | ((unsigned)hi[7] << 16);
    ul.x = (unsigned)lo[0] | ((unsigned)lo[1] << 16);
    ul.y = (unsigned)lo[2] | ((unsigned)lo[3] << 16);
    ul.z = (unsigned)lo[4] | ((unsigned)lo[5] << 16);
    ul.w = (unsigned)lo[6] | ((unsigned)lo[7] << 16);
    __shared__ uint4 sh_hi[256], sh_lo[256];
    sh_hi[lane * 4 + wid] = uh;
    sh_lo[lane * 4 + wid] = ul;
    __syncthreads();
    const int k8 = t >> 2, fpr = t & 3;         // k8 chunk, frame-in-block
    const int s = k8 >> 1, h = k8 & 1;
    const size_t o = (((size_t)b * 32 + s) * 2 + h) * 1024 + f0 + fpr;
    fhi[o] = sh_hi[t];
    flo[o] = sh_lo[t];
}

// ------- kernel 2: split-bf16 MFMA Gram + in-register row/col min & batch max -------
__global__ __launch_bounds__(256) void dist_kernel(const uint4* __restrict__ fhi,
                                                   const uint4* __restrict__ flo,
                                                   const float* __restrict__ sq,
                                                   float* __restrict__ dist,
                                                   unsigned* __restrict__ ctrl,
                                                   unsigned* __restrict__ rmin) {
    const int b = blockIdx.x & 7;               // batch = id&7 -> XCD-pinned operand panels
    int tri = blockIdx.x >> 3, rt = 0;          // 0..35 -> upper-tri tile (rt <= ct)
    while (tri >= 8 - rt) { tri -= 8 - rt; ++rt; }
    const int ct = rt + tri;
    const bool diag = (rt == ct);
    const int tid = threadIdx.x;
    const int w = tid >> 6, lane = tid & 63;
    const int R = rt * 128 + (w & 1) * 64;      // wave rows (2 tiles of 32)
    const int C = ct * 128 + (w >> 1) * 64;     // wave cols
    const int h = lane >> 5, fr = lane & 31;

    size_t a0 = ((size_t)b * 64 + h) * 1024 + R + fr;   // uint4 units; +2048 per k16-step
    size_t b0 = ((size_t)b * 64 + h) * 1024 + C + fr;

    f32x16 acc00, acc01, acc10, acc11;
    #pragma unroll
    for (int i = 0; i < 16; ++i) { acc00[i] = 0.f; acc01[i] = 0.f; acc10[i] = 0.f; acc11[i] = 0.f; }

    bf16x8 A0h = *(const bf16x8*)(fhi + a0), A1h = *(const bf16x8*)(fhi + a0 + 32);
    bf16x8 A0l = *(const bf16x8*)(flo + a0), A1l = *(const bf16x8*)(flo + a0 + 32);
    bf16x8 B0h = *(const bf16x8*)(fhi + b0), B1h = *(const bf16x8*)(fhi + b0 + 32);
    bf16x8 B0l = *(const bf16x8*)(flo + b0), B1l = *(const bf16x8*)(flo + b0 + 32);

    #pragma unroll 4
    for (int s = 0; s < 32; ++s) {
        const bf16x8 cA0h = A0h, cA1h = A1h, cA0l = A0l, cA1l = A1l;
        const bf16x8 cB0h = B0h, cB1h = B1h, cB0l = B0l, cB1l = B1l;
        if (s < 31) {
            a0 += 2048; b0 += 2048;
            A0h = *(const bf16x8*)(fhi + a0); A1h = *(const bf16x8*)(fhi + a0 + 32);
            A0l = *(const bf16x8*)(flo + a0); A1l = *(const bf16x8*)(flo + a0 + 32);
            B0h = *(const bf16x8*)(fhi + b0); B1h = *(const bf16x8*)(fhi + b0 + 32);
            B0l = *(const bf16x8*)(flo + b0); B1l = *(const bf16x8*)(flo + b0 + 32);
        }
        acc00 = __builtin_amdgcn_mfma_f32_32x32x16_bf16(cA0h, cB0h, acc00, 0, 0, 0);
        acc01 = __builtin_amdgcn_mfma_f32_32x32x16_bf16(cA0h, cB1h, acc01, 0, 0, 0);
        acc10 = __builtin_amdgcn_mfma_f32_32x32x16_bf16(cA1h, cB0h, acc10, 0, 0, 0);
        acc11 = __builtin_amdgcn_mfma_f32_32x32x16_bf16(cA1h, cB1h, acc11, 0, 0, 0);
        acc00 = __builtin_amdgcn_mfma_f32_32x32x16_bf16(cA0h, cB0l, acc00, 0, 0, 0);
        acc01 = __builtin_amdgcn_mfma_f32_32x32x16_bf16(cA0h, cB1l, acc01, 0, 0, 0);
        acc10 = __builtin_amdgcn_mfma_f32_32x32x16_bf16(cA1h, cB0l, acc10, 0, 0, 0);
        acc11 = __builtin_amdgcn_mfma_f32_32x32x16_bf16(cA1h, cB1l, acc11, 0, 0, 0);
        acc00 = __builtin_amdgcn_mfma_f32_32x32x16_bf16(cA0l, cB0h, acc00, 0, 0, 0);
        acc01 = __builtin_amdgcn_mfma_f32_32x32x16_bf16(cA0l, cB1h, acc01, 0, 0, 0);
        acc10 = __builtin_amdgcn_mfma_f32_32x32x16_bf16(cA1l, cB0h, acc10, 0, 0, 0);
        acc11 = __builtin_amdgcn_mfma_f32_32x32x16_bf16(cA1l, cB1h, acc11, 0, 0, 0);
    }

    // ---- in-place transform: acc = dist value sqrt(max(sqr+sqc-2*acc,0))/sqrt(C) ----
    const int bF = b * FF;
    const float sqc0 = sq[bF + C + fr], sqc1 = sq[bF + C + fr + 32];
    #pragma unroll
    for (int reg = 0; reg < 16; ++reg) {
        const int rp = 4 * h + (reg & 3) + 8 * (reg >> 2);   // 0..31
        const float sqr0 = sq[bF + R + rp];
        const float sqr1 = sq[bF + R + rp + 32];
        acc00[reg] = sqrtf(fmaxf(sqr0 + sqc0 - 2.0f * acc00[reg], 0.f)) * RCP_SQRT_C;
        acc01[reg] = sqrtf(fmaxf(sqr0 + sqc1 - 2.0f * acc01[reg], 0.f)) * RCP_SQRT_C;
        acc10[reg] = sqrtf(fmaxf(sqr1 + sqc0 - 2.0f * acc10[reg], 0.f)) * RCP_SQRT_C;
        acc11[reg] = sqrtf(fmaxf(sqr1 + sqc1 - 2.0f * acc11[reg], 0.f)) * RCP_SQRT_C;
    }

    // ---- register row/col stats: atomicMin per row (u32 bits, exact), batch max ----
    float mx = 0.f;
    #pragma unroll
    for (int reg = 0; reg < 16; ++reg) {
        const int rp = 4 * h + (reg & 3) + 8 * (reg >> 2);
        float w00 = acc00[reg], w01 = acc01[reg], w10 = acc10[reg], w11 = acc11[reg];
        float x00 = w00, x01 = w01, x10 = w10, x11 = w11;
        if (diag) {                              // exclude self-distance from min; 0 for max
            if (C + fr == R + rp)           { w00 = FLT_MAX; x00 = 0.f; }
            if (C + 32 + fr == R + rp)      { w01 = FLT_MAX; x01 = 0.f; }
            if (C + fr == R + 32 + rp)      { w10 = FLT_MAX; x10 = 0.f; }
            if (C + 32 + fr == R + 32 + rp) { w11 = FLT_MAX; x11 = 0.f; }
        }
        mx = fmaxf(mx, fmaxf(fmaxf(x00, x01), fmaxf(x10, x11)));
        float r0 = fminf(w00, w01);              // row R+rp over this wave's 64 cols
        float r1 = fminf(w10, w11);              // row R+32+rp
        #pragma unroll
        for (int off = 1; off < 32; off <<= 1) { // stays within 32-lane half (same row)
            r0 = fminf(r0, __shfl_xor(r0, off));
            r1 = fminf(r1, __shfl_xor(r1, off));
        }
        if (fr == 0) {                           // lanes 0 (h=0) and 32 (h=1), distinct rows
            atomicMin(&rmin[bF + R + rp], __float_as_uint(r0));
            atomicMin(&rmin[bF + R + 32 + rp], __float_as_uint(r1));
        }
    }
    if (!diag) {                                 // mirror rows: per-column min over 64 rows
        float c0 = FLT_MAX, c1 = FLT_MAX;
        #pragma unroll
        for (int reg = 0; reg < 16; ++reg) {
            c0 = fminf(c0, fminf(acc00[reg], acc10[reg]));
            c1 = fminf(c1, fminf(acc01[reg], acc11[reg]));
        }
        c0 = fminf(c0, __shfl_xor(c0, 32));      // combine h halves (rows +-4)
        c1 = fminf(c1, __shfl_xor(c1, 32));
        if (h == 0) {
            atomicMin(&rmin[bF + C + fr], __float_as_uint(c0));
            atomicMin(&rmin[bF + C + 32 + fr], __float_as_uint(c1));
        }
    }
    #pragma unroll
    for (int off = 1; off < 64; off <<= 1) mx = fmaxf(mx, __shfl_xor(mx, off));
    if (lane == 0) atomicMax(&ctrl[b], __float_as_uint(mx));

    // ---- epilogue: two phases through a 64x128 LDS stage; mirrored stores ----
    __shared__ float lds[64 * LP];
    const int R0 = rt * 128, C0 = ct * 128;
    const int lcb = (w >> 1) * 64 + fr;         // local col base in 0..127

    #pragma unroll
    for (int p = 0; p < 2; ++p) {
        if ((w & 1) == p) {                     // this wave's rows belong to phase p
            #pragma unroll
            for (int reg = 0; reg < 16; ++reg) {
                const int rp = 4 * h + (reg & 3) + 8 * (reg >> 2);   // 0..31
                lds[rp * LP + lcb]            = acc00[reg];
                lds[rp * LP + lcb + 32]       = acc01[reg];
                lds[(rp + 32) * LP + lcb]     = acc10[reg];
                lds[(rp + 32) * LP + lcb + 32] = acc11[reg];
            }
        }
        __syncthreads();
        if (!diag) {
            for (int q = tid; q < 64 * 128; q += 256) {
                const int lr = q >> 7, c = q & 127;
                dist[((size_t)bF + R0 + p * 64 + lr) * FF + C0 + c] = lds[lr * LP + c];
            }
            for (int q = tid; q < 64 * 128; q += 256) {
                const int lr = q & 63, c = q >> 6;
                dist[((size_t)bF + C0 + c) * FF + R0 + p * 64 + lr] = lds[lr * LP + c];
            }
        } else if (p == 0) {
            for (int q = tid; q < 64 * 128; q += 256) {
                const int i = q >> 7, j = q & 127;
                const float v = (i == j) ? 0.f : (i < j ? lds[i * LP + j] : lds[j * LP + i]);
                dist[((size_t)bF + R0 + i) * FF + C0 + j] = v;
            }
            for (int q = tid; q < 64 * 64; q += 256) {
                const int i = 64 + (q >> 6), j = q & 63;
                dist[((size_t)bF + R0 + i) * FF + C0 + j] = lds[j * LP + i];
            }
        } else {
            for (int q = tid; q < 64 * 64; q += 256) {
                const int i = 64 + (q >> 6), j = 64 + (q & 63);
                const float v = (i == j) ? 0.f
                               : (i < j ? lds[(i - 64) * LP + j] : lds[(j - 64) * LP + i]);
                dist[((size_t)bF + R0 + i) * FF + C0 + j] = v;
            }
        }
        __syncthreads();
    }
}

// ---- kernel 3: masked min -> score (density on the fly) + last-block top-81 ----
__global__ __launch_bounds__(256) void scoretop_kernel(const float* __restrict__ dist,
                                                       const unsigned* __restrict__ rmin,
                                                       const float* __restrict__ noise,
                                                       unsigned* __restrict__ ctrl,
                                                       float* __restrict__ score,
                                                       int* __restrict__ selsort) {
    const int t = threadIdx.x, wid = t >> 6, lane = t & 63;
    const int r = blockIdx.x * 4 + wid;
    const int b = r >> 10, bF = b * FF;

    // density vector for this batch: 16 cols per lane at lane*4 + j*256 (+q)
    float4 e0, e1, e2, e3;
    #define MKE(EJ, J) { \
        const uint4 rm = *(const uint4*)(rmin + bF + lane * 4 + (J) * 256); \
        const float4 nz = *(const float4*)(noise + bF + lane * 4 + (J) * 256); \
        EJ.x = densf(__uint_as_float(rm.x), nz.x); \
        EJ.y = densf(__uint_as_float(rm.y), nz.y); \
        EJ.z = densf(__uint_as_float(rm.z), nz.z); \
        EJ.w = densf(__uint_as_float(rm.w), nz.w); }
    MKE(e0, 0) MKE(e1, 1) MKE(e2, 2) MKE(e3, 3)
    #undef MKE

    // own density: extracted from the same e-vector (uniform switch + shfl broadcast)
    const int dcol = r & 1023;
    const int osel = ((dcol >> 8) << 2) | (dcol & 3);   // wave-uniform
    const int olane = (dcol & 255) >> 2;
    float own;
    switch (osel) {
        case 0:  own = e0.x; break; case 1:  own = e0.y; break;
        case 2:  own = e0.z; break; case 3:  own = e0.w; break;
        case 4:  own = e1.x; break; case 5:  own = e1.y; break;
        case 6:  own = e1.z; break; case 7:  own = e1.w; break;
        case 8:  own = e2.x; break; case 9:  own = e2.y; break;
        case 10: own = e2.z; break; case 11: own = e2.w; break;
        case 12: own = e3.x; break; case 13: own = e3.y; break;
        case 14: own = e3.z; break; default: own = e3.w; break;
    }
    const float dme = __shfl(own, olane);

    const float* dr = dist + (size_t)r * FF + lane * 4;
    float mn = FLT_MAX;
    {
        const float4 d0 = *(const float4*)(dr);
        const float4 d1 = *(const float4*)(dr + 256);
        const float4 d2 = *(const float4*)(dr + 512);
        const float4 d3 = *(const float4*)(dr + 768);
        mn = fminf(mn, (e0.x > dme) ? d0.x : FLT_MAX);
        mn = fminf(mn, (e0.y > dme) ? d0.y : FLT_MAX);
        mn = fminf(mn, (e0.z > dme) ? d0.z : FLT_MAX);
        mn = fminf(mn, (e0.w > dme) ? d0.w : FLT_MAX);
        mn = fminf(mn, (e1.x > dme) ? d1.x : FLT_MAX);
        mn = fminf(mn, (e1.y > dme) ? d1.y : FLT_MAX);
        mn = fminf(mn, (e1.z > dme) ? d1.z : FLT_MAX);
        mn = fminf(mn, (e1.w > dme) ? d1.w : FLT_MAX);
        mn = fminf(mn, (e2.x > dme) ? d2.x : FLT_MAX);
        mn = fminf(mn, (e2.y > dme) ? d2.y : FLT_MAX);
        mn = fminf(mn, (e2.z > dme) ? d2.z : FLT_MAX);
        mn = fminf(mn, (e2.w > dme) ? d2.w : FLT_MAX);
        mn = fminf(mn, (e3.x > dme) ? d3.x : FLT_MAX);
        mn = fminf(mn, (e3.y > dme) ? d3.y : FLT_MAX);
        mn = fminf(mn, (e3.z > dme) ? d3.z : FLT_MAX);
        mn = fminf(mn, (e3.w > dme) ? d3.w : FLT_MAX);
    }
    #pragma unroll
    for (int off = 32; off > 0; off >>= 1) mn = fminf(mn, __shfl_down(mn, off));
    if (lane == 0) {
        const float dmaxb = __uint_as_float(ctrl[b]);
        score[r] = ((mn == FLT_MAX) ? dmaxb : mn) * dme;
        __threadfence();                         // release this wave's score write
    }
    __syncthreads();

    // ---- last block of this batch (256 blocks/batch) runs the radix top-81 ----
    __shared__ int slast;
    unsigned* bcnt = ctrl + 8;
    if (t == 0) slast = (atomicAdd(&bcnt[b], 1u) == 255u) ? 1 : 0;
    __syncthreads();
    if (!slast) return;
    __threadfence();                             // acquire other blocks' scores

    const volatile float* sb = score + (size_t)b * FF;
    unsigned v[4];
    #pragma unroll
    for (int j = 0; j < 4; ++j) v[j] = __float_as_uint(sb[t + 256 * j]);

    __shared__ unsigned hist[256];
    __shared__ unsigned wtot[4];
    __shared__ unsigned sh_byte, sh_kk;
    unsigned prefix = 0, kk = TOK;
    #pragma unroll
    for (int pass = 0; pass < 4; ++pass) {
        const int sh = 24 - 8 * pass;
        const unsigned pmask = (pass == 0) ? 0u : (0xFFFFFFFFu << (sh + 8));
        hist[t] = 0;
        __syncthreads();
        #pragma unroll
        for (int j = 0; j < 4; ++j)
            if ((v[j] & pmask) == prefix) atomicAdd(&hist[(v[j] >> sh) & 255], 1u);
        __syncthreads();
        const unsigned cnt = hist[t];
        unsigned s = cnt;
        #pragma unroll
        for (int off = 1; off < 64; off <<= 1) {
            const unsigned o = __shfl_down(s, off);
            if (lane + off < 64) s += o;
        }
        if (lane == 0) wtot[wid] = s;
        __syncthreads();
        unsigned hi2 = 0;
        for (int w2 = wid + 1; w2 < 4; ++w2) hi2 += wtot[w2];
        const unsigned S_incl = s + hi2;
        const unsigned S_excl = S_incl - cnt;
        if (S_excl < kk && kk <= S_incl) { sh_byte = (unsigned)t; sh_kk = kk - S_excl; }
        __syncthreads();
        prefix |= (sh_byte << sh);
        kk = sh_kk;
    }
    const unsigned T = prefix;                   // exact 81st-largest value (bits)

    __shared__ unsigned cgt[16], ceq[16];
    unsigned long long bgt[4], beq[4];
    #pragma unroll
    for (int j = 0; j < 4; ++j) {
        bgt[j] = __ballot(v[j] > T);
        beq[j] = __ballot(v[j] == T);
        if (lane == 0) {
            cgt[j * 4 + wid] = (unsigned)__popcll(bgt[j]);
            ceq[j * 4 + wid] = (unsigned)__popcll(beq[j]);
        }
    }
    __syncthreads();
    const unsigned long long below = (1ULL << lane) - 1ULL;
    #pragma unroll
    for (int j = 0; j < 4; ++j) {
        const bool gt = v[j] > T, eq = v[j] == T;
        if (!gt && !eq) continue;
        const int c = j * 4 + wid;
        unsigned bq_gt = 0, bq_eq = 0;
        for (int cc = 0; cc < c; ++cc) { bq_gt += cgt[cc]; bq_eq += ceq[cc]; }
        const unsigned wgt = (unsigned)__popcll(bgt[j] & below);
        const unsigned weq = (unsigned)__popcll(beq[j] & below);
        unsigned pos_;
        if (gt) {
            const unsigned eq_before = bq_eq + weq;
            pos_ = bq_gt + wgt + ((eq_before < kk) ? eq_before : kk);
        } else {
            const unsigned eord = bq_eq + weq;
            if (eord >= kk) continue;
            pos_ = bq_gt + wgt + eord;
        }
        selsort[b * TOK + pos_] = (int)(t + 256 * j);
    }
}

// ---------------- kernel 4: gather + pos-embed ----------------
__global__ __launch_bounds__(256) void gather_kernel(const float* __restrict__ x,
                                                     const float* __restrict__ pos,
                                                     const int* __restrict__ selsort,
                                                     float* __restrict__ out) {
    const size_t i = (size_t)blockIdx.x * 256 + threadIdx.x;
    const size_t total = (size_t)BB * TOK * NJ * (CH / 4);
    if (i >= total) return;
    const int c4 = (int)(i & (CH / 4 - 1));
    size_t r = i >> 7;
    const int n = (int)(r % NJ); r /= NJ;
    const int t = (int)(r % TOK);
    const int b = (int)(r / TOK);
    const int f = selsort[b * TOK + t];
    float4 v = *(const float4*)(x + (((size_t)(b * FF + f)) * NJ + n) * CH + c4 * 4);
    const float4 p = *(const float4*)(pos + (size_t)t * CH + c4 * 4);
    v.x += p.x; v.y += p.y; v.z += p.z; v.w += p.w;
    *(float4*)(out + i * 4) = v;
}

extern "C" void kernel_launch(void* const* d_in, const int* in_sizes, int n_in,
                              void* d_out, int out_size, void* d_ws, size_t ws_size,
                              hipStream_t stream) {
    const float* x     = (const float*)d_in[0];
    const float* pos   = (const float*)d_in[1];
    const float* noise = (const float*)d_in[2];
    float* out = (float*)d_out;

    uint4* fhi    = (uint4*)d_ws;                           // 8.4 MB
    uint4* flo    = fhi + (size_t)BB * 32 * 2 * 1024;       // 8.4 MB
    float* dist   = (float*)(flo + (size_t)BB * 32 * 2 * 1024);  // 33.5 MB
    float* sq      = dist + (size_t)BB * FF * FF;
    unsigned* ctrl = (unsigned*)(sq + BB * FF);             // dmx[8] + bcnt[8]
    unsigned* rmin = ctrl + 16;                             // 8192 u32
    float* score   = (float*)(rmin + BB * FF);
    int*   selsort = (int*)(score + BB * FF);

    pool_kernel<<<(BB * FF) / 4, 256, 0, stream>>>(x, fhi, flo, sq, ctrl, rmin);
    dist_kernel<<<288, 256, 0, stream>>>(fhi, flo, sq, dist, ctrl, rmin);
    scoretop_kernel<<<(BB * FF) / 4, 256, 0, stream>>>(dist, rmin, noise, ctrl, score, selsort);
    const int gtot = (int)(((size_t)BB * TOK * NJ * (CH / 4) + 255) / 256);
    gather_kernel<<<gtot, 256, 0, stream>>>(x, pos, selsort, out);
}

// Round 5
// 483.353 us; speedup vs baseline: 1.4640x; 1.4640x over previous
//
#include <hip/hip_runtime.h>
#include <math.h>
#include <float.h>

#define BB 8
#define FF 1024
#define NJ 17
#define CH 512
#define TOK 81
#define RCP_SQRT_C 0.04419417382415922f   // 1/sqrt(512)
#define LP 133                            // LDS row pad (stride%32=5, conflict-free col reads)

typedef short bf16x8 __attribute__((ext_vector_type(8)));   // 8 bf16 = 4 VGPRs
typedef float f32x16 __attribute__((ext_vector_type(16)));  // 32x32 MFMA acc

static __device__ inline unsigned short f2bf(float f) {
    __bf16 h = (__bf16)f;                       // RNE
    return __builtin_bit_cast(unsigned short, h);
}
static __device__ inline float bf2f(unsigned short u) {
    return (float)__builtin_bit_cast(__bf16, u);
}

// frag layout: [b][s(32)][h(2)][f(1024)][j(8)] bf16, uint4 index ((b*32+s)*2+h)*1024 + f

// ---------------- kernel 1: mean over joints + sumsq + hi/lo frag write -------
__global__ __launch_bounds__(256) void pool_kernel(const float* __restrict__ x,
                                                   uint4* __restrict__ fhi,
                                                   uint4* __restrict__ flo,
                                                   float* __restrict__ sq,
                                                   unsigned* __restrict__ dmx) {
    const int t = threadIdx.x;
    if (blockIdx.x == 0 && t < BB) dmx[t] = 0u;   // init distmax accumulators (>=0 floats)
    const int wid = t >> 6, lane = t & 63;
    const int row0 = blockIdx.x * 4;            // 4 rows per block, one wave per row
    const int row = row0 + wid;
    const int b = row >> 10, f0 = row0 & 1023;
    const float* px = x + (size_t)row * NJ * CH + lane * 8;
    float a[8] = {};
    #pragma unroll
    for (int n = 0; n < NJ; ++n) {
        const float4 v0 = *(const float4*)(px + (size_t)n * CH);
        const float4 v1 = *(const float4*)(px + (size_t)n * CH + 4);
        a[0] += v0.x; a[1] += v0.y; a[2] += v0.z; a[3] += v0.w;
        a[4] += v1.x; a[5] += v1.y; a[6] += v1.z; a[7] += v1.w;
    }
    float ssq = 0.f;
    unsigned short hi[8], lo[8];
    #pragma unroll
    for (int j = 0; j < 8; ++j) {
        const float m = a[j] / 17.0f;
        ssq += m * m;
        hi[j] = f2bf(m);
        lo[j] = f2bf(m - bf2f(hi[j]));
    }
    #pragma unroll
    for (int off = 32; off > 0; off >>= 1) ssq += __shfl_down(ssq, off);
    if (lane == 0) sq[row] = ssq;

    uint4 uh, ul;
    uh.x = (unsigned)hi[0] | ((unsigned)hi[1] << 16);
    uh.y = (unsigned)hi[2] | ((unsigned)hi[3] << 16);
    uh.z = (unsigned)hi[4] | ((unsigned)hi[5] << 16);
    uh.w = (unsigned)hi[6] | ((unsigned)hi[7] << 16);
    ul.x = (unsigned)lo[0] | ((unsigned)lo[1] << 16);
    ul.y = (unsigned)lo[2] | ((unsigned)lo[3] << 16);
    ul.z = (unsigned)lo[4] | ((unsigned)lo[5] << 16);
    ul.w = (unsigned)lo[6] | ((unsigned)lo[7] << 16);
    __shared__ uint4 sh_hi[256], sh_lo[256];
    sh_hi[lane * 4 + wid] = uh;
    sh_lo[lane * 4 + wid] = ul;
    __syncthreads();
    const int k8 = t >> 2, fpr = t & 3;         // k8 chunk, frame-in-block
    const int s = k8 >> 1, h = k8 & 1;
    const size_t o = (((size_t)b * 32 + s) * 2 + h) * 1024 + f0 + fpr;
    fhi[o] = sh_hi[t];
    flo[o] = sh_lo[t];
}

// ------- kernel 2: split-bf16 MFMA Gram, upper-tri tiles, mirrored store -------
// Flat grid of 288; batch = id & 7 so the id%8 -> XCD round-robin pins each batch's
// 2 MB operand panel set onto one XCD's L2 (perf-only remap).
__global__ __launch_bounds__(256) void dist_kernel(const uint4* __restrict__ fhi,
                                                   const uint4* __restrict__ flo,
                                                   const float* __restrict__ sq,
                                                   float* __restrict__ dist) {
    const int b = blockIdx.x & 7;
    int tri = blockIdx.x >> 3, rt = 0;          // 0..35 -> upper-tri tile (rt <= ct)
    while (tri >= 8 - rt) { tri -= 8 - rt; ++rt; }
    const int ct = rt + tri;
    const bool diag = (rt == ct);
    const int tid = threadIdx.x;
    const int w = tid >> 6, lane = tid & 63;
    const int R = rt * 128 + (w & 1) * 64;      // wave rows (2 tiles of 32)
    const int C = ct * 128 + (w >> 1) * 64;     // wave cols
    const int h = lane >> 5, fr = lane & 31;

    size_t a0 = ((size_t)b * 64 + h) * 1024 + R + fr;   // uint4 units; +2048 per k16-step
    size_t b0 = ((size_t)b * 64 + h) * 1024 + C + fr;

    f32x16 acc00, acc01, acc10, acc11;
    #pragma unroll
    for (int i = 0; i < 16; ++i) { acc00[i] = 0.f; acc01[i] = 0.f; acc10[i] = 0.f; acc11[i] = 0.f; }

    bf16x8 A0h = *(const bf16x8*)(fhi + a0), A1h = *(const bf16x8*)(fhi + a0 + 32);
    bf16x8 A0l = *(const bf16x8*)(flo + a0), A1l = *(const bf16x8*)(flo + a0 + 32);
    bf16x8 B0h = *(const bf16x8*)(fhi + b0), B1h = *(const bf16x8*)(fhi + b0 + 32);
    bf16x8 B0l = *(const bf16x8*)(flo + b0), B1l = *(const bf16x8*)(flo + b0 + 32);

    #pragma unroll 4
    for (int s = 0; s < 32; ++s) {
        const bf16x8 cA0h = A0h, cA1h = A1h, cA0l = A0l, cA1l = A1l;
        const bf16x8 cB0h = B0h, cB1h = B1h, cB0l = B0l, cB1l = B1l;
        if (s < 31) {
            a0 += 2048; b0 += 2048;
            A0h = *(const bf16x8*)(fhi + a0); A1h = *(const bf16x8*)(fhi + a0 + 32);
            A0l = *(const bf16x8*)(flo + a0); A1l = *(const bf16x8*)(flo + a0 + 32);
            B0h = *(const bf16x8*)(fhi + b0); B1h = *(const bf16x8*)(fhi + b0 + 32);
            B0l = *(const bf16x8*)(flo + b0); B1l = *(const bf16x8*)(flo + b0 + 32);
        }
        acc00 = __builtin_amdgcn_mfma_f32_32x32x16_bf16(cA0h, cB0h, acc00, 0, 0, 0);
        acc01 = __builtin_amdgcn_mfma_f32_32x32x16_bf16(cA0h, cB1h, acc01, 0, 0, 0);
        acc10 = __builtin_amdgcn_mfma_f32_32x32x16_bf16(cA1h, cB0h, acc10, 0, 0, 0);
        acc11 = __builtin_amdgcn_mfma_f32_32x32x16_bf16(cA1h, cB1h, acc11, 0, 0, 0);
        acc00 = __builtin_amdgcn_mfma_f32_32x32x16_bf16(cA0h, cB0l, acc00, 0, 0, 0);
        acc01 = __builtin_amdgcn_mfma_f32_32x32x16_bf16(cA0h, cB1l, acc01, 0, 0, 0);
        acc10 = __builtin_amdgcn_mfma_f32_32x32x16_bf16(cA1h, cB0l, acc10, 0, 0, 0);
        acc11 = __builtin_amdgcn_mfma_f32_32x32x16_bf16(cA1h, cB1l, acc11, 0, 0, 0);
        acc00 = __builtin_amdgcn_mfma_f32_32x32x16_bf16(cA0l, cB0h, acc00, 0, 0, 0);
        acc01 = __builtin_amdgcn_mfma_f32_32x32x16_bf16(cA0l, cB1h, acc01, 0, 0, 0);
        acc10 = __builtin_amdgcn_mfma_f32_32x32x16_bf16(cA1l, cB0h, acc10, 0, 0, 0);
        acc11 = __builtin_amdgcn_mfma_f32_32x32x16_bf16(cA1l, cB1h, acc11, 0, 0, 0);
    }

    // ---- epilogue: two phases through a 64x128 LDS stage; mirrored stores ----
    __shared__ float lds[64 * LP];
    const int bF = b * FF;
    const int R0 = rt * 128, C0 = ct * 128;
    const float sqc0 = sq[bF + C + fr], sqc1 = sq[bF + C + fr + 32];
    const int lcb = (w >> 1) * 64 + fr;         // local col base in 0..127

    #pragma unroll
    for (int p = 0; p < 2; ++p) {
        if ((w & 1) == p) {                     // this wave's rows belong to phase p
            #pragma unroll
            for (int reg = 0; reg < 16; ++reg) {
                const int rp = 4 * h + (reg & 3) + 8 * (reg >> 2);   // 0..31
                const float sqr0 = sq[bF + R + rp];
                const float sqr1 = sq[bF + R + rp + 32];
                lds[rp * LP + lcb] =
                    sqrtf(fmaxf(sqr0 + sqc0 - 2.0f * acc00[reg], 0.f)) * RCP_SQRT_C;
                lds[rp * LP + lcb + 32] =
                    sqrtf(fmaxf(sqr0 + sqc1 - 2.0f * acc01[reg], 0.f)) * RCP_SQRT_C;
                lds[(rp + 32) * LP + lcb] =
                    sqrtf(fmaxf(sqr1 + sqc0 - 2.0f * acc10[reg], 0.f)) * RCP_SQRT_C;
                lds[(rp + 32) * LP + lcb + 32] =
                    sqrtf(fmaxf(sqr1 + sqc1 - 2.0f * acc11[reg], 0.f)) * RCP_SQRT_C;
            }
        }
        __syncthreads();
        if (!diag) {
            // direct: rows R0+p*64+lr, cols C0..C0+127 (coalesced)
            for (int q = tid; q < 64 * 128; q += 256) {
                const int lr = q >> 7, c = q & 127;
                dist[((size_t)bF + R0 + p * 64 + lr) * FF + C0 + c] = lds[lr * LP + c];
            }
            // mirror: rows C0+c, cols R0+p*64+lr (lanes along lr -> coalesced)
            for (int q = tid; q < 64 * 128; q += 256) {
                const int lr = q & 63, c = q >> 6;
                dist[((size_t)bF + C0 + c) * FF + R0 + p * 64 + lr] = lds[lr * LP + c];
            }
        } else if (p == 0) {
            // rows i=0..63, all cols: canonical upper value (0 on diagonal)
            for (int q = tid; q < 64 * 128; q += 256) {
                const int i = q >> 7, j = q & 127;
                const float v = (i == j) ? 0.f : (i < j ? lds[i * LP + j] : lds[j * LP + i]);
                dist[((size_t)bF + R0 + i) * FF + C0 + j] = v;
            }
            // rows i=64..127, cols j=0..63: mirror of staged (j, i)
            for (int q = tid; q < 64 * 64; q += 256) {
                const int i = 64 + (q >> 6), j = q & 63;
                dist[((size_t)bF + R0 + i) * FF + C0 + j] = lds[j * LP + i];
            }
        } else {
            // rows i=64..127, cols j=64..127: canonical within staged rows 64..127
            for (int q = tid; q < 64 * 64; q += 256) {
                const int i = 64 + (q >> 6), j = 64 + (q & 63);
                const float v = (i == j) ? 0.f
                               : (i < j ? lds[(i - 64) * LP + j] : lds[(j - 64) * LP + i]);
                dist[((size_t)bF + R0 + i) * FF + C0 + j] = v;
            }
        }
        __syncthreads();
    }
}

__device__ inline void merge2(float& lo0, float& lo1, float c0, float c1) {
    float n0 = fminf(lo0, c0);
    float n1 = fminf(fmaxf(lo0, c0), fminf(lo1, c1));
    lo0 = n0; lo1 = n1;
}

// ------- kernel 3: per-row two-smallest + rowmax -> density; fused batch max -------
// float4 loads: 16 B/lane, exact (min/max reductions are order-independent)
__global__ __launch_bounds__(256) void rowstat_kernel(const float* __restrict__ dist,
                                                      const float* __restrict__ noise,
                                                      float* __restrict__ density,
                                                      unsigned* __restrict__ dmx) {
    const int wid = threadIdx.x >> 6;
    const int r = blockIdx.x * 4 + wid;
    const int lane = threadIdx.x & 63;
    const float* dr = dist + (size_t)r * FF + lane * 4;
    float lo0 = FLT_MAX, lo1 = FLT_MAX, mx = -FLT_MAX;
    #pragma unroll
    for (int j = 0; j < 4; ++j) {
        const float4 d = *(const float4*)(dr + j * 256);
        mx = fmaxf(mx, fmaxf(fmaxf(d.x, d.y), fmaxf(d.z, d.w)));
        merge2(lo0, lo1, fminf(d.x, d.y), fmaxf(d.x, d.y));
        merge2(lo0, lo1, fminf(d.z, d.w), fmaxf(d.z, d.w));
    }
    #pragma unroll
    for (int off = 32; off > 0; off >>= 1) {
        const float o0 = __shfl_down(lo0, off);
        const float o1 = __shfl_down(lo1, off);
        const float om = __shfl_down(mx, off);
        merge2(lo0, lo1, o0, o1);
        mx = fmaxf(mx, om);
    }
    __shared__ float wmx[4];
    if (lane == 0) {
        density[r] = expf(-0.5f * (lo0 * lo0 + lo1 * lo1)) + noise[r] * 1e-6f;
        wmx[wid] = mx;
    }
    __syncthreads();
    if (threadIdx.x == 0) {
        const float m = fmaxf(fmaxf(wmx[0], wmx[1]), fmaxf(wmx[2], wmx[3]));
        // distances are >= 0, so float bits compare monotonically as unsigned
        atomicMax(&dmx[blockIdx.x >> 8], __float_as_uint(m));
    }
}

// ---------------- kernel 4: per-row masked min -> score ----------------
__global__ __launch_bounds__(256) void scoremin_kernel(const float* __restrict__ dist,
                                                       const float* __restrict__ density,
                                                       const float* __restrict__ distmax,
                                                       float* __restrict__ score) {
    const int r = blockIdx.x * 4 + (threadIdx.x >> 6);
    const int lane = threadIdx.x & 63;
    const int b = r >> 10;
    const float* dr = dist + (size_t)r * FF + lane * 4;
    const float* db = density + (size_t)b * FF + lane * 4;
    const float dme = density[r];
    float mn = FLT_MAX;
    #pragma unroll
    for (int j = 0; j < 4; ++j) {
        const float4 d = *(const float4*)(dr + j * 256);
        const float4 de = *(const float4*)(db + j * 256);
        mn = fminf(mn, (de.x > dme) ? d.x : FLT_MAX);
        mn = fminf(mn, (de.y > dme) ? d.y : FLT_MAX);
        mn = fminf(mn, (de.z > dme) ? d.z : FLT_MAX);
        mn = fminf(mn, (de.w > dme) ? d.w : FLT_MAX);
    }
    #pragma unroll
    for (int off = 32; off > 0; off >>= 1) mn = fminf(mn, __shfl_down(mn, off));
    if (lane == 0) {
        if (mn == FLT_MAX) mn = distmax[b];
        score[r] = mn * dme;
    }
}

// -------- kernel 5: exact top-81 via MSB byte-radix select + ballot compaction --------
// Selection set: all scores > T plus the kk smallest-index scores == T, where T is the
// 81st-largest value. Matches lax.top_k stable (smallest-index-first) tie semantics.
// Output written directly in ascending index order.
__global__ __launch_bounds__(256) void topk_kernel(const float* __restrict__ score,
                                                   int* __restrict__ selsort) {
    const int b = blockIdx.x, t = threadIdx.x;
    const int w = t >> 6, lane = t & 63;
    const float* sb = score + b * FF;
    // scores are >= 0 (dist >= 0, density > 0) -> bits compare monotonically as unsigned
    unsigned v[4];
    #pragma unroll
    for (int j = 0; j < 4; ++j) v[j] = __float_as_uint(sb[t + 256 * j]);   // index i = t + 256*j

    __shared__ unsigned hist[256];
    __shared__ unsigned wtot[4];
    __shared__ unsigned sh_byte, sh_kk;
    unsigned prefix = 0, kk = TOK;
    #pragma unroll
    for (int pass = 0; pass < 4; ++pass) {
        const int sh = 24 - 8 * pass;
        const unsigned pmask = (pass == 0) ? 0u : (0xFFFFFFFFu << (sh + 8));
        hist[t] = 0;
        __syncthreads();
        #pragma unroll
        for (int j = 0; j < 4; ++j)
            if ((v[j] & pmask) == prefix) atomicAdd(&hist[(v[j] >> sh) & 255], 1u);
        __syncthreads();
        const unsigned cnt = hist[t];           // bin t count
        unsigned s = cnt;                       // inclusive suffix over lanes within wave
        #pragma unroll
        for (int off = 1; off < 64; off <<= 1) {
            const unsigned o = __shfl_down(s, off);
            if (lane + off < 64) s += o;
        }
        if (lane == 0) wtot[w] = s;
        __syncthreads();
        unsigned hi2 = 0;
        for (int w2 = w + 1; w2 < 4; ++w2) hi2 += wtot[w2];
        const unsigned S_incl = s + hi2;        // count of values in bins >= t
        const unsigned S_excl = S_incl - cnt;   // count of values in bins >  t
        if (S_excl < kk && kk <= S_incl) { sh_byte = (unsigned)t; sh_kk = kk - S_excl; }
        __syncthreads();
        prefix |= (sh_byte << sh);
        kk = sh_kk;
    }
    const unsigned T = prefix;                  // exact 81st-largest value (bits)

    // --- compaction: emit indices of (v > T) plus first-kk (v == T), index-ascending ---
    __shared__ unsigned cgt[16], ceq[16];       // per-64-chunk counts, chunk c = i>>6 = j*4+w
    unsigned long long bgt[4], beq[4];
    #pragma unroll
    for (int j = 0; j < 4; ++j) {
        bgt[j] = __ballot(v[j] > T);
        beq[j] = __ballot(v[j] == T);
        if (lane == 0) {
            cgt[j * 4 + w] = (unsigned)__popcll(bgt[j]);
            ceq[j * 4 + w] = (unsigned)__popcll(beq[j]);
        }
    }
    __syncthreads();
    const unsigned long long below = (1ULL << lane) - 1ULL;   // lanes < lane
    #pragma unroll
    for (int j = 0; j < 4; ++j) {
        const bool gt = v[j] > T, eq = v[j] == T;
        if (!gt && !eq) continue;
        const int c = j * 4 + w;
        unsigned bq_gt = 0, bq_eq = 0;
        for (int cc = 0; cc < c; ++cc) { bq_gt += cgt[cc]; bq_eq += ceq[cc]; }
        const unsigned wgt = (unsigned)__popcll(bgt[j] & below);
        const unsigned weq = (unsigned)__popcll(beq[j] & below);
        unsigned pos;
        if (gt) {
            const unsigned eq_before = bq_eq + weq;
            pos = bq_gt + wgt + ((eq_before < kk) ? eq_before : kk);
        } else {
            const unsigned e = bq_eq + weq;     // global tie rank (index order)
            if (e >= kk) continue;
            pos = bq_gt + wgt + e;
        }
        selsort[b * TOK + pos] = (int)(t + 256 * j);
    }
}

// ---------------- kernel 6: gather + pos-embed ----------------
__global__ __launch_bounds__(256) void gather_kernel(const float* __restrict__ x,
                                                     const float* __restrict__ pos,
                                                     const int* __restrict__ selsort,
                                                     float* __restrict__ out) {
    const size_t i = (size_t)blockIdx.x * 256 + threadIdx.x;
    const size_t total = (size_t)BB * TOK * NJ * (CH / 4);
    if (i >= total) return;
    const int c4 = (int)(i & (CH / 4 - 1));
    size_t r = i >> 7;
    const int n = (int)(r % NJ); r /= NJ;
    const int t = (int)(r % TOK);
    const int b = (int)(r / TOK);
    const int f = selsort[b * TOK + t];
    float4 v = *(const float4*)(x + (((size_t)(b * FF + f)) * NJ + n) * CH + c4 * 4);
    const float4 p = *(const float4*)(pos + (size_t)t * CH + c4 * 4);
    v.x += p.x; v.y += p.y; v.z += p.z; v.w += p.w;
    *(float4*)(out + i * 4) = v;
}

extern "C" void kernel_launch(void* const* d_in, const int* in_sizes, int n_in,
                              void* d_out, int out_size, void* d_ws, size_t ws_size,
                              hipStream_t stream) {
    const float* x     = (const float*)d_in[0];
    const float* pos   = (const float*)d_in[1];
    const float* noise = (const float*)d_in[2];
    float* out = (float*)d_out;

    uint4* fhi    = (uint4*)d_ws;                           // 8 MB
    uint4* flo    = fhi + (size_t)BB * 32 * 2 * 1024;       // 8 MB
    float* dist   = (float*)(flo + (size_t)BB * 32 * 2 * 1024);  // 33.5 MB
    float* sq     = dist + (size_t)BB * FF * FF;
    float* density = sq + BB * FF;
    float* distmax = density + BB * FF;                     // 8 floats (atomicMax as uint)
    float* score   = distmax + 8;
    int*   selsort = (int*)(score + BB * FF);

    pool_kernel<<<(BB * FF) / 4, 256, 0, stream>>>(x, fhi, flo, sq, (unsigned*)distmax);
    dist_kernel<<<288, 256, 0, stream>>>(fhi, flo, sq, dist);   // flat grid, batch = id&7
    rowstat_kernel<<<(BB * FF) / 4, 256, 0, stream>>>(dist, noise, density, (unsigned*)distmax);
    scoremin_kernel<<<(BB * FF) / 4, 256, 0, stream>>>(dist, density, distmax, score);
    topk_kernel<<<BB, 256, 0, stream>>>(score, selsort);
    const int gtot = (int)(((size_t)BB * TOK * NJ * (CH / 4) + 255) / 256);
    gather_kernel<<<gtot, 256, 0, stream>>>(x, pos, selsort, out);
}